// Round 3
// baseline (234.064 us; speedup 1.0000x reference)
//
#include <hip/hip_runtime.h>
#include <cstdint>
#include <cstddef>

#define NUM_LAYERS 20
#define HID 1024
#define M_TOTAL 8192
#define BM 32

typedef __attribute__((ext_vector_type(8))) short bf16x8;
typedef __attribute__((ext_vector_type(4))) float floatx4;
typedef __attribute__((ext_vector_type(4))) float f32x4;
typedef __attribute__((ext_vector_type(8))) unsigned short u16x8;

__device__ __forceinline__ unsigned short f2bf(float f) {
  union { float f; unsigned int u; } v; v.f = f;
  unsigned int r = v.u + 0x7fffu + ((v.u >> 16) & 1u);  // RNE
  return (unsigned short)(r >> 16);
}

__device__ __forceinline__ u16x8 pack8(f32x4 a, f32x4 b) {
  u16x8 o;
  o[0] = f2bf(a[0]); o[1] = f2bf(a[1]); o[2] = f2bf(a[2]); o[3] = f2bf(a[3]);
  o[4] = f2bf(b[0]); o[5] = f2bf(b[1]); o[6] = f2bf(b[2]); o[7] = f2bf(b[3]);
  return o;
}

__device__ __forceinline__ bf16x8 pack8bf(f32x4 a, f32x4 b) {
  union { u16x8 u; bf16x8 s; } c;
  c.u = pack8(a, b);
  return c.s;
}

// ---- Kernel 1: conv_w 20-layer sum -> bf16 wb [N=1024][K=1024].
// 40 float4 NT loads in flight per thread; HBM-bound at ~84% peak (80 MiB read).
__global__ __launch_bounds__(256, 1) void wsum_kernel(const float* __restrict__ w,
                                                      unsigned short* __restrict__ wb) {
  const int P = blockIdx.x * 256 + threadIdx.x;  // ushort8 output index
  const f32x4* p = reinterpret_cast<const f32x4*>(w);
  f32x4 va[NUM_LAYERS], vb[NUM_LAYERS];
#pragma unroll
  for (int l = 0; l < NUM_LAYERS; ++l) {
    const f32x4* pl = p + (size_t)l * (HID * HID / 4) + (size_t)2 * P;
    va[l] = __builtin_nontemporal_load(pl);
    vb[l] = __builtin_nontemporal_load(pl + 1);
  }
  f32x4 s0 = va[0], s1 = vb[0];
#pragma unroll
  for (int l = 1; l < NUM_LAYERS; ++l) { s0 += va[l]; s1 += vb[l]; }
  reinterpret_cast<u16x8*>(wb)[P] = pack8(s0, s1);
}

// ---- Kernel 2: fused GEMM + RMSNorm, NO LDS staging, NO K-loop barriers ----
// BM=32 rows x full N=1024 per block; 512 threads = 8 waves (1M x 8N), wave tile
// 32x128 = 2x8 frags of 16x16x32 bf16 MFMA.
// Round-2 post-mortem: B has ZERO intra-block reuse (each wave owns disjoint
// N-columns), so LDS-staging B bought nothing and its 133 KB + barrier-per-step
// drain made the kernel latency-bound (MfmaUtil 9.6%, occupancy 20%). Now:
//   - B frags: global_load_dwordx4 direct from L2-resident wb (2 MB, reused
//     across all 256 blocks via per-XCD L2).
//   - A frags: global_load_dwordx4 x2 direct from fp32 x + in-reg RNE cvt
//     (8-wave redundancy served by L1: per-step A slab is 4 KB).
//   - 2-deep named register pipeline (static indexing): loads for step t+1 in
//     flight under step t's 16 MFMAs; compiler inserts counted vmcnt.
// C never touches DRAM: per-row ssq in-register + 1 KB LDS cross-wave reduce.
__global__ __launch_bounds__(512, 2) void gemm_norm_kernel(const float* __restrict__ x,
                                                           const unsigned short* __restrict__ wb,
                                                           const float* __restrict__ nw,
                                                           float* __restrict__ out) {
  __shared__ float lred[8][32];  // cross-wave row-ssq partials

  const int tid = threadIdx.x;
  const int lane = tid & 63;
  const int w = tid >> 6;       // wave 0..7 -> N columns w*128..w*128+127
  const int quad = lane >> 4;   // 0..3 -> K sub-slice quad*8
  const int mrow = lane & 15;
  const int m0 = blockIdx.x * BM;

  // Per-lane fragment base pointers. w is wave-uniform -> compiler can fold the
  // j*32KB term into SGPR saddr bases with one shared voffset.
  const unsigned short* bp[8];
#pragma unroll
  for (int j = 0; j < 8; ++j)
    bp[j] = wb + (size_t)(w * 128 + j * 16 + mrow) * HID + quad * 8;
  const float* ap[2];
#pragma unroll
  for (int i = 0; i < 2; ++i)
    ap[i] = x + (size_t)(m0 + i * 16 + mrow) * HID + quad * 8;

  floatx4 acc[2][8] = {};
  bf16x8 B0[8], B1[8];
  f32x4 A0[2][2], A1[2][2];

#define LOADB(B, koff)                                                         \
  {                                                                            \
    _Pragma("unroll") for (int j = 0; j < 8; ++j)                              \
        B[j] = *reinterpret_cast<const bf16x8*>(bp[j] + (koff));               \
  }
#define LOADA(A, koff)                                                         \
  {                                                                            \
    _Pragma("unroll") for (int i = 0; i < 2; ++i) {                            \
      A[i][0] = *reinterpret_cast<const f32x4*>(ap[i] + (koff));               \
      A[i][1] = *reinterpret_cast<const f32x4*>(ap[i] + (koff) + 4);           \
    }                                                                          \
  }
#define COMPUTE(B, A)                                                          \
  {                                                                            \
    bf16x8 af0 = pack8bf(A[0][0], A[0][1]);                                    \
    bf16x8 af1 = pack8bf(A[1][0], A[1][1]);                                    \
    _Pragma("unroll") for (int j = 0; j < 8; ++j) {                            \
      acc[0][j] = __builtin_amdgcn_mfma_f32_16x16x32_bf16(af0, B[j], acc[0][j], 0, 0, 0); \
      acc[1][j] = __builtin_amdgcn_mfma_f32_16x16x32_bf16(af1, B[j], acc[1][j], 0, 0, 0); \
    }                                                                          \
  }

  // Prologue: steps 0 and 1 in flight.
  LOADB(B0, 0);  LOADA(A0, 0);
  LOADB(B1, 32); LOADA(A1, 32);

  // 15 double-steps: compute step 2i / 2i+1 while loading 2i+2 / 2i+3.
  for (int it = 0; it < 15; ++it) {
    COMPUTE(B0, A0);
    LOADB(B0, 64); LOADA(A0, 64);
    COMPUTE(B1, A1);
    LOADB(B1, 96); LOADA(A1, 96);
#pragma unroll
    for (int j = 0; j < 8; ++j) bp[j] += 64;
    ap[0] += 64; ap[1] += 64;
  }
  COMPUTE(B0, A0);  // step 30
  COMPUTE(B1, A1);  // step 31

#undef LOADB
#undef LOADA
#undef COMPUTE

  // --- fused RMSNorm epilogue. C/D layout: col=lane&15, row=quad*4+reg.
  // Per-lane partial ssq over this wave's 8 col-frags, reduce across the 16
  // lanes of the quad-row (xor bits 0..3), then cross-wave via lred.
  float ps[2][4];
#pragma unroll
  for (int i = 0; i < 2; ++i)
#pragma unroll
    for (int r = 0; r < 4; ++r) {
      float s = 0.f;
#pragma unroll
      for (int j = 0; j < 8; ++j) { float v = acc[i][j][r]; s += v * v; }
#pragma unroll
      for (int off = 1; off < 16; off <<= 1) s += __shfl_xor(s, off, 64);
      ps[i][r] = s;
    }
  if (mrow == 0) {
#pragma unroll
    for (int i = 0; i < 2; ++i)
#pragma unroll
      for (int r = 0; r < 4; ++r)
        lred[w][i * 16 + quad * 4 + r] = ps[i][r];
  }
  __syncthreads();

  // scale = sqrt(H) * rsqrt(sum C^2 + 400*eps*H); /20 folded in (C is raw dot)
  float scale[2][4];
#pragma unroll
  for (int i = 0; i < 2; ++i)
#pragma unroll
    for (int r = 0; r < 4; ++r) {
      float s = 0.f;
#pragma unroll
      for (int ww = 0; ww < 8; ++ww) s += lred[ww][i * 16 + quad * 4 + r];
      scale[i][r] = 32.0f * rsqrtf(s + 0.4096f);  // 0.4096 = eps*H*400
    }

  float nwv[8];
#pragma unroll
  for (int j = 0; j < 8; ++j) nwv[j] = nw[w * 128 + j * 16 + mrow];

  // Plain (cached) stores: each quad's 8 j-chunks fill 512 contiguous bytes per
  // row -> L2 write-combines to full lines (round-2 NT stores showed WRITE_SIZE
  // 52 MB vs 33.5 ideal).
#pragma unroll
  for (int i = 0; i < 2; ++i)
#pragma unroll
    for (int r = 0; r < 4; ++r) {
      float* orow = out + (size_t)(m0 + i * 16 + quad * 4 + r) * HID + w * 128 + mrow;
      const float sc = scale[i][r];
#pragma unroll
      for (int j = 0; j < 8; ++j)
        orow[j * 16] = acc[i][j][r] * sc * nwv[j];
    }
}

extern "C" void kernel_launch(void* const* d_in, const int* in_sizes, int n_in,
                              void* d_out, int out_size, void* d_ws, size_t ws_size,
                              hipStream_t stream) {
  const float* x = (const float*)d_in[0];       // [2,4096,1024] fp32
  const float* conv_w = (const float*)d_in[1];  // [20,1024,1024] fp32
  const float* norm_w = (const float*)d_in[2];  // [1024] fp32
  float* out = (float*)d_out;                   // [2,4096,1024] fp32

  unsigned short* wb = (unsigned short*)d_ws;   // 2 MiB: summed W bf16 [N][K]

  wsum_kernel<<<512, 256, 0, stream>>>(conv_w, wb);
  gemm_norm_kernel<<<M_TOTAL / BM, 512, 0, stream>>>(x, wb, norm_w, out);
}

// Round 4
// 211.382 us; speedup vs baseline: 1.1073x; 1.1073x over previous
//
#include <hip/hip_runtime.h>
#include <cstdint>
#include <cstddef>

#define NUM_LAYERS 20
#define HID 1024
#define M_TOTAL 8192
#define BM 32

typedef __attribute__((ext_vector_type(8))) short bf16x8;
typedef __attribute__((ext_vector_type(4))) float floatx4;
typedef __attribute__((ext_vector_type(4))) float f32x4;
typedef __attribute__((ext_vector_type(8))) unsigned short u16x8;

__device__ __forceinline__ unsigned short f2bf(float f) {
  union { float f; unsigned int u; } v; v.f = f;
  unsigned int r = v.u + 0x7fffu + ((v.u >> 16) & 1u);  // RNE
  return (unsigned short)(r >> 16);
}

__device__ __forceinline__ u16x8 pack8(f32x4 a, f32x4 b) {
  u16x8 o;
  o[0] = f2bf(a[0]); o[1] = f2bf(a[1]); o[2] = f2bf(a[2]); o[3] = f2bf(a[3]);
  o[4] = f2bf(b[0]); o[5] = f2bf(b[1]); o[6] = f2bf(b[2]); o[7] = f2bf(b[3]);
  return o;
}

__device__ __forceinline__ bf16x8 pack8bf(f32x4 a, f32x4 b) {
  union { u16x8 u; bf16x8 s; } c;
  c.u = pack8(a, b);
  return c.s;
}

// ---- Kernel 1: conv_w 20-layer sum -> bf16 wb, FRAGMENT-PACKED layout ----
// Element (n,k) stored at ushort8 index ((n>>4)*32 + (k>>5))*64 + ((k>>3)&3)*16
// + (n&15), so a GEMM wave's B-fragment load is 64 lanes x consecutive 16 B =
// one coalesced 1 KB burst (round-3 scatter fix). Reads unchanged (coalesced,
// HBM-bound ~84%); writes become scattered 16 B but total only 2 MB.
__global__ __launch_bounds__(256, 1) void wsum_kernel(const float* __restrict__ w,
                                                      unsigned short* __restrict__ wb) {
  const int P = blockIdx.x * 256 + threadIdx.x;  // source ushort8 index
  const f32x4* p = reinterpret_cast<const f32x4*>(w);
  f32x4 va[NUM_LAYERS], vb[NUM_LAYERS];
#pragma unroll
  for (int l = 0; l < NUM_LAYERS; ++l) {
    const f32x4* pl = p + (size_t)l * (HID * HID / 4) + (size_t)2 * P;
    va[l] = __builtin_nontemporal_load(pl);
    vb[l] = __builtin_nontemporal_load(pl + 1);
  }
  f32x4 s0 = va[0], s1 = vb[0];
#pragma unroll
  for (int l = 1; l < NUM_LAYERS; ++l) { s0 += va[l]; s1 += vb[l]; }
  const int n = P >> 7;             // row 0..1023
  const int k0 = (P & 127) * 8;     // k 0..1016, multiple of 8
  const int D = ((n >> 4) * 32 + (k0 >> 5)) * 64 + ((k0 >> 3) & 3) * 16 + (n & 15);
  reinterpret_cast<u16x8*>(wb)[D] = pack8(s0, s1);
}

// ---- Kernel 2: fused GEMM + RMSNorm, coalesced direct loads, no barriers ----
// BM=32 rows x full N=1024 per block; 512 threads = 8 waves (1M x 8N), wave
// tile 32x128 = 2x8 frags of 16x16x32 bf16 MFMA. Grid 256 = 1 block/CU.
// Round-3 post-mortem: scattered 16-line fragment loads + 1-step A lookahead
// at 2 waves/SIMD = latency-bound 102 us. Fixes:
//   - B frags from fragment-packed wb: 1 KB coalesced bursts, NT (L1 bypass),
//     double-buffered with load-for-(s+2) issued at step s.
//   - A frags direct from fp32 x (rows shared by all 8 waves -> L1 hits),
//     4-buffered: load-for-(s+4) issued at step s covers ~900 cy HBM latency.
//   - (512,1): VGPR budget 256 (1 block/CU is grid-forced anyway). ~24 loads
//     in flight/wave, all statically indexed.
// Floor: per-CU 2 MB B-stream through L1 at ~64 B/cy ~= 14 us.
__global__ __launch_bounds__(512, 1) void gemm_norm_kernel(const float* __restrict__ x,
                                                           const unsigned short* __restrict__ wb,
                                                           const float* __restrict__ nw,
                                                           float* __restrict__ out) {
  __shared__ float lred[8][32];  // cross-wave row-ssq partials

  const int tid = threadIdx.x;
  const int lane = tid & 63;
  const int w = tid >> 6;       // wave 0..7 -> N columns w*128..w*128+127
  const int quad = lane >> 4;   // 0..3 -> K sub-slice quad*8
  const int mrow = lane & 15;
  const int m0 = blockIdx.x * BM;

  // B fragment stream base: frag j covers n1 = w*8+j; step s at +s*512 ushorts.
  const unsigned short* bp[8];
#pragma unroll
  for (int j = 0; j < 8; ++j)
    bp[j] = wb + (size_t)(w * 8 + j) * 32 * 512 + lane * 8;
  const float* ap[2];
#pragma unroll
  for (int i = 0; i < 2; ++i)
    ap[i] = x + (size_t)(m0 + i * 16 + mrow) * HID + quad * 8;

  floatx4 acc[2][8] = {};
  bf16x8 B0[8], B1[8];
  f32x4 A0[2][2], A1[2][2], A2[2][2], A3[2][2];

#define LOADB(B, uoff)                                                         \
  {                                                                            \
    _Pragma("unroll") for (int j = 0; j < 8; ++j)                              \
        B[j] = __builtin_nontemporal_load(                                     \
            reinterpret_cast<const bf16x8*>(bp[j] + (uoff)));                  \
  }
#define LOADA(A, foff)                                                         \
  {                                                                            \
    _Pragma("unroll") for (int i = 0; i < 2; ++i) {                            \
      A[i][0] = *reinterpret_cast<const f32x4*>(ap[i] + (foff));               \
      A[i][1] = *reinterpret_cast<const f32x4*>(ap[i] + (foff) + 4);           \
    }                                                                          \
  }
#define COMPUTE(B, A)                                                          \
  {                                                                            \
    bf16x8 af0 = pack8bf(A[0][0], A[0][1]);                                    \
    bf16x8 af1 = pack8bf(A[1][0], A[1][1]);                                    \
    _Pragma("unroll") for (int j = 0; j < 8; ++j) {                            \
      acc[0][j] = __builtin_amdgcn_mfma_f32_16x16x32_bf16(af0, B[j], acc[0][j], 0, 0, 0); \
      acc[1][j] = __builtin_amdgcn_mfma_f32_16x16x32_bf16(af1, B[j], acc[1][j], 0, 0, 0); \
    }                                                                          \
  }

  // Prologue: B for steps 0,1; A for steps 0..3.
  LOADB(B0, 0);    LOADA(A0, 0);
  LOADB(B1, 512);  LOADA(A1, 32);
  LOADA(A2, 64);   LOADA(A3, 96);

  // 7 iterations x 4 steps = steps 0..27. Per step s: compute, then issue
  // B for s+2 (offset (c+2)*512 ushorts) and A for s+4 (offset (c+4)*32 floats).
  for (int it = 0; it < 7; ++it) {
    COMPUTE(B0, A0); LOADB(B0, 1024); LOADA(A0, 128);
    COMPUTE(B1, A1); LOADB(B1, 1536); LOADA(A1, 160);
    COMPUTE(B0, A2); LOADB(B0, 2048); LOADA(A2, 192);
    COMPUTE(B1, A3); LOADB(B1, 2560); LOADA(A3, 224);
#pragma unroll
    for (int j = 0; j < 8; ++j) bp[j] += 2048;  // 4 steps x 512 ushorts
    ap[0] += 128; ap[1] += 128;                 // 4 steps x 32 floats
  }
  // Tail: steps 28..31 (A already loaded; B for 30,31 issued here).
  COMPUTE(B0, A0); LOADB(B0, 1024);
  COMPUTE(B1, A1); LOADB(B1, 1536);
  COMPUTE(B0, A2);
  COMPUTE(B1, A3);

#undef LOADB
#undef LOADA
#undef COMPUTE

  // --- fused RMSNorm epilogue. C/D layout: col=lane&15, row=quad*4+reg.
  float ps[2][4];
#pragma unroll
  for (int i = 0; i < 2; ++i)
#pragma unroll
    for (int r = 0; r < 4; ++r) {
      float s = 0.f;
#pragma unroll
      for (int j = 0; j < 8; ++j) { float v = acc[i][j][r]; s += v * v; }
#pragma unroll
      for (int off = 1; off < 16; off <<= 1) s += __shfl_xor(s, off, 64);
      ps[i][r] = s;
    }
  if (mrow == 0) {
#pragma unroll
    for (int i = 0; i < 2; ++i)
#pragma unroll
      for (int r = 0; r < 4; ++r)
        lred[w][i * 16 + quad * 4 + r] = ps[i][r];
  }
  __syncthreads();

  // scale = sqrt(H) * rsqrt(sum C^2 + 400*eps*H); /20 folded in (C is raw dot)
  float scale[2][4];
#pragma unroll
  for (int i = 0; i < 2; ++i)
#pragma unroll
    for (int r = 0; r < 4; ++r) {
      float s = 0.f;
#pragma unroll
      for (int ww = 0; ww < 8; ++ww) s += lred[ww][i * 16 + quad * 4 + r];
      scale[i][r] = 32.0f * rsqrtf(s + 0.4096f);  // 0.4096 = eps*H*400
    }

  float nwv[8];
#pragma unroll
  for (int j = 0; j < 8; ++j) nwv[j] = nw[w * 128 + j * 16 + mrow];

  // Plain (cached) stores: quad's 8 j-chunks fill contiguous 512 B spans; L2
  // write-combines (round-3 confirmed WRITE_SIZE ~= 32 MB ideal).
#pragma unroll
  for (int i = 0; i < 2; ++i)
#pragma unroll
    for (int r = 0; r < 4; ++r) {
      float* orow = out + (size_t)(m0 + i * 16 + quad * 4 + r) * HID + w * 128 + mrow;
      const float sc = scale[i][r];
#pragma unroll
      for (int j = 0; j < 8; ++j)
        orow[j * 16] = acc[i][j][r] * sc * nwv[j];
    }
}

extern "C" void kernel_launch(void* const* d_in, const int* in_sizes, int n_in,
                              void* d_out, int out_size, void* d_ws, size_t ws_size,
                              hipStream_t stream) {
  const float* x = (const float*)d_in[0];       // [2,4096,1024] fp32
  const float* conv_w = (const float*)d_in[1];  // [20,1024,1024] fp32
  const float* norm_w = (const float*)d_in[2];  // [1024] fp32
  float* out = (float*)d_out;                   // [2,4096,1024] fp32

  unsigned short* wb = (unsigned short*)d_ws;   // 2 MiB: summed W bf16, packed

  wsum_kernel<<<512, 256, 0, stream>>>(conv_w, wb);
  gemm_norm_kernel<<<M_TOTAL / BM, 512, 0, stream>>>(x, wb, norm_w, out);
}

// Round 5
// 194.240 us; speedup vs baseline: 1.2050x; 1.0883x over previous
//
#include <hip/hip_runtime.h>
#include <cstdint>
#include <cstddef>

#define NUM_LAYERS 20
#define HID 1024
#define M_TOTAL 8192

typedef __attribute__((ext_vector_type(8))) short bf16x8;
typedef __attribute__((ext_vector_type(4))) float floatx4;
typedef __attribute__((ext_vector_type(4))) float f32x4;
typedef __attribute__((ext_vector_type(8))) unsigned short u16x8;

typedef __attribute__((address_space(1))) unsigned int as1_u32;
typedef __attribute__((address_space(3))) unsigned int as3_u32;

__device__ __forceinline__ unsigned short f2bf(float f) {
  union { float f; unsigned int u; } v; v.f = f;
  unsigned int r = v.u + 0x7fffu + ((v.u >> 16) & 1u);  // RNE
  return (unsigned short)(r >> 16);
}

__device__ __forceinline__ float bf2f(unsigned short u) {
  union { unsigned int u; float f; } v; v.u = ((unsigned int)u) << 16;
  return v.f;
}

__device__ __forceinline__ u16x8 pack8(f32x4 a, f32x4 b) {
  u16x8 o;
  o[0] = f2bf(a[0]); o[1] = f2bf(a[1]); o[2] = f2bf(a[2]); o[3] = f2bf(a[3]);
  o[4] = f2bf(b[0]); o[5] = f2bf(b[1]); o[6] = f2bf(b[2]); o[7] = f2bf(b[3]);
  return o;
}

// async global->LDS, 16B/lane; LDS ptr must be wave-uniform base (HW adds lane*16)
__device__ __forceinline__ void load16_lds(const void* g, void* l) {
  __builtin_amdgcn_global_load_lds(
      reinterpret_cast<as1_u32*>(reinterpret_cast<uintptr_t>(g)),
      reinterpret_cast<as3_u32*>(reinterpret_cast<uintptr_t>(l)),
      16, 0, 0);
}

// ---- Kernel 1: fused prep (round-0 proven). wsum blocks FIRST so their
// MLP-bound waves overlap with the BW-bound xcast waves.
// Blocks 0..511:    conv_w 20-layer sum -> bf16 wb [N][K] row-major.
// Blocks 512..2559: x fp32->bf16 cast, 4 float4 loads + 2 ushort8 stores/thr.
__global__ __launch_bounds__(256, 1) void prep_kernel(const float* __restrict__ x,
                                                      const float* __restrict__ w,
                                                      unsigned short* __restrict__ xb,
                                                      unsigned short* __restrict__ wb) {
  const int b = blockIdx.x;
  const int t = threadIdx.x;
  if (b < 512) {
    const int P = b * 256 + t;  // ushort8 output index; float4 pair (2P, 2P+1)
    const f32x4* p = reinterpret_cast<const f32x4*>(w);
    f32x4 va[NUM_LAYERS], vb[NUM_LAYERS];
#pragma unroll
    for (int l = 0; l < NUM_LAYERS; ++l) {
      const f32x4* pl = p + (size_t)l * (HID * HID / 4) + (size_t)2 * P;
      va[l] = __builtin_nontemporal_load(pl);
      vb[l] = __builtin_nontemporal_load(pl + 1);
    }
    f32x4 s0 = va[0], s1 = vb[0];
#pragma unroll
    for (int l = 1; l < NUM_LAYERS; ++l) { s0 += va[l]; s1 += vb[l]; }
    reinterpret_cast<u16x8*>(wb)[P] = pack8(s0, s1);
  } else {
    const int bb = b - 512;
#pragma unroll
    for (int j = 0; j < 2; ++j) {
      const int P = bb * 512 + t + j * 256;  // ushort8 output index
      const f32x4* p = reinterpret_cast<const f32x4*>(x) + (size_t)2 * P;
      f32x4 v0 = __builtin_nontemporal_load(p);
      f32x4 v1 = __builtin_nontemporal_load(p + 1);
      reinterpret_cast<u16x8*>(xb)[P] = pack8(v0, v1);
    }
  }
}

// ---- Kernel 2: GEMM C[M][N] = A[M][K] @ B[N][K]^T, bf16 in/out, m97 structure.
// 256x128 tile (MxN), BK=32, 512 threads = 8 waves as 4M x 2N, wave tile 64x64
// (4x4 of 16x16x32 MFMA). Grid 32x8 = 256 blocks = 1/CU.
// Tile choice from the round-4 model: runtime ~ staged bytes/CU at ~25 B/cy
// effective L2->CU rate; this shape is 0.77 MB/CU (vs 2.3 MB fused round-4,
// 1.5 MB round-0 128x64) -> predicted 15-22 us.
// Grid map: mb = bid&31 -> the 8 blocks sharing an A-panel sit on one XCD
// (default bid%8 XCD round-robin), so each A panel is HBM-fetched once.
__global__ __launch_bounds__(512, 2) void gemm_kernel(const unsigned short* __restrict__ A,
                                                      const unsigned short* __restrict__ B,
                                                      unsigned short* __restrict__ Cb) {
  __shared__ unsigned short lA[256 * 32];  // 16 KiB
  __shared__ unsigned short lB[128 * 32];  // 8 KiB

  const int tid = threadIdx.x;
  const int lane = tid & 63;
  const int w = tid >> 6;      // wave 0..7
  const int wr = w >> 1;       // 0..3 -> M quarter
  const int wc = w & 1;        // 0..1 -> N half
  const int quad = lane >> 4;  // 0..3
  const int mrow = lane & 15;

  const int bid = blockIdx.x;
  const int mb = bid & 31;  // 32 M-tiles; same-A blocks land on one XCD
  const int nb = bid >> 5;  // 8 N-tiles
  const int m0 = mb * 256;
  const int n0 = nb * 128;

  const int srow = tid >> 2;          // 0..127
  const int skoff = (tid & 3) * 8;    // k elems
  const unsigned short* gA = A + (size_t)(m0 + srow) * HID + skoff;
  const unsigned short* gB = B + (size_t)(n0 + srow) * HID + skoff;

  // wave-uniform LDS dest bases (ushort units); HW adds lane*16 B
  unsigned short* dA0 = lA + w * 512;
  unsigned short* dA1 = lA + 4096 + w * 512;
  unsigned short* dB0 = lB + w * 512;

  floatx4 acc[4][4] = {};

  const unsigned short* ra[4];
  const unsigned short* rb[4];
#pragma unroll
  for (int i = 0; i < 4; ++i)
    ra[i] = lA + (wr * 64 + i * 16 + mrow) * 32 + quad * 8;
#pragma unroll
  for (int j = 0; j < 4; ++j)
    rb[j] = lB + (wc * 64 + j * 16 + mrow) * 32 + quad * 8;

  for (int k0 = 0; k0 < HID; k0 += 32) {
    __syncthreads();
    load16_lds(gA,                     dA0);
    load16_lds(gA + (size_t)128 * HID, dA1);
    load16_lds(gB,                     dB0);
    gA += 32;
    gB += 32;
    __syncthreads();

    bf16x8 af[4], bfr[4];
#pragma unroll
    for (int i = 0; i < 4; ++i) af[i] = *reinterpret_cast<const bf16x8*>(ra[i]);
#pragma unroll
    for (int j = 0; j < 4; ++j) bfr[j] = *reinterpret_cast<const bf16x8*>(rb[j]);
#pragma unroll
    for (int i = 0; i < 4; ++i)
#pragma unroll
      for (int j = 0; j < 4; ++j)
        acc[i][j] = __builtin_amdgcn_mfma_f32_16x16x32_bf16(af[i], bfr[j], acc[i][j], 0, 0, 0);
  }

  // epilogue: verified C/D mapping (round-0 passed): out row = quad*4 + r within
  // the A-frag, out col = mrow within the B-frag.
  const int row_base = m0 + wr * 64 + quad * 4;
  const int col_base = n0 + wc * 64 + mrow;
#pragma unroll
  for (int i = 0; i < 4; ++i) {
#pragma unroll
    for (int j = 0; j < 4; ++j) {
#pragma unroll
      for (int r = 0; r < 4; ++r) {
        int row = row_base + i * 16 + r;
        Cb[(size_t)row * HID + col_base + j * 16] = f2bf(acc[i][j][r]);
      }
    }
  }
}

// ---- Kernel 3: RMS norm (round-0 proven), one WAVE per row ----
// out = C * 32 * rsqrt(sum C^2 + 400*eps*H) * norm_w   (/20 folded into scale)
__global__ __launch_bounds__(256) void rmsnorm_kernel(const unsigned short* __restrict__ Cb,
                                                      const float* __restrict__ nw,
                                                      float* __restrict__ out) {
  const int row = blockIdx.x * 4 + (threadIdx.x >> 6);
  const int lane = threadIdx.x & 63;
  const u16x8* src = reinterpret_cast<const u16x8*>(Cb) + (size_t)row * 128;
  f32x4 v[2][2];
  float ss = 0.f;
#pragma unroll
  for (int j = 0; j < 2; ++j) {
    u16x8 u = src[lane + j * 64];
#pragma unroll
    for (int h = 0; h < 2; ++h) {
#pragma unroll
      for (int e = 0; e < 4; ++e) {
        float f = bf2f(u[h * 4 + e]);
        v[j][h][e] = f;
        ss += f * f;
      }
    }
  }
#pragma unroll
  for (int off = 32; off > 0; off >>= 1) ss += __shfl_xor(ss, off, 64);
  const float scale = 32.0f * rsqrtf(ss + 0.4096f);  // 32=sqrt(H); 0.4096 = eps*H*400
  const f32x4* nwp = reinterpret_cast<const f32x4*>(nw);
  f32x4* dst = reinterpret_cast<f32x4*>(out) + (size_t)row * 256;
#pragma unroll
  for (int j = 0; j < 2; ++j) {
#pragma unroll
    for (int h = 0; h < 2; ++h) {
      const int fi = 2 * (lane + j * 64) + h;
      f32x4 wv = nwp[fi];
      f32x4 o = v[j][h] * scale * wv;
      __builtin_nontemporal_store(o, dst + fi);
    }
  }
}

extern "C" void kernel_launch(void* const* d_in, const int* in_sizes, int n_in,
                              void* d_out, int out_size, void* d_ws, size_t ws_size,
                              hipStream_t stream) {
  const float* x = (const float*)d_in[0];       // [2,4096,1024] fp32
  const float* conv_w = (const float*)d_in[1];  // [20,1024,1024] fp32
  const float* norm_w = (const float*)d_in[2];  // [1024] fp32
  float* out = (float*)d_out;                   // [2,4096,1024] fp32

  unsigned short* xb = (unsigned short*)d_ws;       // 16 MiB: A bf16
  unsigned short* wb = xb + (size_t)M_TOTAL * HID;  // +2 MiB: summed W bf16 [N][K]
  unsigned short* cb = wb + (size_t)HID * HID;      // +16 MiB: C bf16

  prep_kernel<<<512 + 2048, 256, 0, stream>>>(x, conv_w, xb, wb);
  gemm_kernel<<<(M_TOTAL / 256) * (HID / 128), 512, 0, stream>>>(xb, wb, cb);
  rmsnorm_kernel<<<M_TOTAL / 4, 256, 0, stream>>>(cb, norm_w, out);
}

// Round 6
// 186.731 us; speedup vs baseline: 1.2535x; 1.0402x over previous
//
#include <hip/hip_runtime.h>
#include <cstdint>
#include <cstddef>

#define NUM_LAYERS 20
#define HID 1024
#define M_TOTAL 8192

typedef __attribute__((ext_vector_type(8))) short bf16x8;
typedef __attribute__((ext_vector_type(4))) float floatx4;
typedef __attribute__((ext_vector_type(4))) float f32x4;
typedef __attribute__((ext_vector_type(8))) unsigned short u16x8;

typedef __attribute__((address_space(1))) unsigned int as1_u32;
typedef __attribute__((address_space(3))) unsigned int as3_u32;

__device__ __forceinline__ unsigned short f2bf(float f) {
  union { float f; unsigned int u; } v; v.f = f;
  unsigned int r = v.u + 0x7fffu + ((v.u >> 16) & 1u);  // RNE
  return (unsigned short)(r >> 16);
}

__device__ __forceinline__ float bf2f(unsigned short u) {
  union { unsigned int u; float f; } v; v.u = ((unsigned int)u) << 16;
  return v.f;
}

__device__ __forceinline__ u16x8 pack8(f32x4 a, f32x4 b) {
  u16x8 o;
  o[0] = f2bf(a[0]); o[1] = f2bf(a[1]); o[2] = f2bf(a[2]); o[3] = f2bf(a[3]);
  o[4] = f2bf(b[0]); o[5] = f2bf(b[1]); o[6] = f2bf(b[2]); o[7] = f2bf(b[3]);
  return o;
}

// async global->LDS, 16B/lane; LDS ptr must be wave-uniform base (HW adds lane*16)
__device__ __forceinline__ void load16_lds(const void* g, void* l) {
  __builtin_amdgcn_global_load_lds(
      reinterpret_cast<as1_u32*>(reinterpret_cast<uintptr_t>(g)),
      reinterpret_cast<as3_u32*>(reinterpret_cast<uintptr_t>(l)),
      16, 0, 0);
}

// ---- Kernel 1: fused prep (proven; ~24 us, near its 20.6 us HBM floor).
// Blocks 0..511:    conv_w 20-layer sum -> bf16 wb [N][K] row-major.
// Blocks 512..2559: x fp32->bf16 cast, 4 float4 loads + 2 ushort8 stores/thr.
__global__ __launch_bounds__(256, 1) void prep_kernel(const float* __restrict__ x,
                                                      const float* __restrict__ w,
                                                      unsigned short* __restrict__ xb,
                                                      unsigned short* __restrict__ wb) {
  const int b = blockIdx.x;
  const int t = threadIdx.x;
  if (b < 512) {
    const int P = b * 256 + t;  // ushort8 output index; float4 pair (2P, 2P+1)
    const f32x4* p = reinterpret_cast<const f32x4*>(w);
    f32x4 va[NUM_LAYERS], vb[NUM_LAYERS];
#pragma unroll
    for (int l = 0; l < NUM_LAYERS; ++l) {
      const f32x4* pl = p + (size_t)l * (HID * HID / 4) + (size_t)2 * P;
      va[l] = __builtin_nontemporal_load(pl);
      vb[l] = __builtin_nontemporal_load(pl + 1);
    }
    f32x4 s0 = va[0], s1 = vb[0];
#pragma unroll
    for (int l = 1; l < NUM_LAYERS; ++l) { s0 += va[l]; s1 += vb[l]; }
    reinterpret_cast<u16x8*>(wb)[P] = pack8(s0, s1);
  } else {
    const int bb = b - 512;
#pragma unroll
    for (int j = 0; j < 2; ++j) {
      const int P = bb * 512 + t + j * 256;  // ushort8 output index
      const f32x4* p = reinterpret_cast<const f32x4*>(x) + (size_t)2 * P;
      f32x4 v0 = __builtin_nontemporal_load(p);
      f32x4 v1 = __builtin_nontemporal_load(p + 1);
      reinterpret_cast<u16x8*>(xb)[P] = pack8(v0, v1);
    }
  }
}

// ---- Kernel 2: GEMM C[M][N] = A[M][K] @ B[N][K]^T, bf16 in/out ----
// m97-proven geometry: 128x128 tile, BK=64, 256 threads = 4 waves (2M x 2N),
// wave tile 64x64 (4x4 of 16x16x32 MFMA, 2 k-halves). Grid 64x8 = 512 blocks
// -> 2-3 blocks/CU: the cross-block wave overlap (m114) that hides the
// per-step vmcnt(0) barrier drain. Round-5 post-mortem: 256x128/512thr gave
// grid=256 = 1 block/CU, no overlap partner -> drain fully exposed (~39 us).
// Per K-step: 8x global_load_lds(16B), then 2 half-steps of
// 8x ds_read_b128 + 16 MFMA -- m97's measured-874-TF inner loop.
// Grid map: mb = bid&63 -> the 8 same-A blocks (nb=0..7) all hit XCD mb%8;
// per-XCD L2 holds 8 A-panels (2 MB) + full B (2 MB) = 4 MB.
__global__ __launch_bounds__(256, 2) void gemm_kernel(const unsigned short* __restrict__ A,
                                                      const unsigned short* __restrict__ B,
                                                      unsigned short* __restrict__ Cb) {
  __shared__ unsigned short lA[128 * 64];  // 16 KiB
  __shared__ unsigned short lB[128 * 64];  // 16 KiB

  const int tid = threadIdx.x;
  const int lane = tid & 63;
  const int w = tid >> 6;      // wave 0..3
  const int wr = w >> 1;       // 0..1 -> M half
  const int wc = w & 1;        // 0..1 -> N half
  const int quad = lane >> 4;  // 0..3
  const int mrow = lane & 15;

  const int bid = blockIdx.x;
  const int mb = bid & 63;  // 64 M-tiles; same-A blocks share an XCD
  const int nb = bid >> 6;  // 8 N-tiles
  const int m0 = mb * 128;
  const int n0 = nb * 128;

  // staging source: thread covers row tid>>3 (0..31 per issue), 16 B at (tid&7)*8
  const int srow = tid >> 3;
  const int skoff = (tid & 7) * 8;
  const unsigned short* gA = A + (size_t)(m0 + srow) * HID + skoff;
  const unsigned short* gB = B + (size_t)(n0 + srow) * HID + skoff;

  // wave-uniform LDS dest bases (ushort units); HW adds lane*16 B
  unsigned short* dA = lA + w * 512;
  unsigned short* dB = lB + w * 512;

  floatx4 acc[4][4] = {};

  const unsigned short* ra[4];
  const unsigned short* rb[4];
#pragma unroll
  for (int i = 0; i < 4; ++i)
    ra[i] = lA + (wr * 64 + i * 16 + mrow) * 64 + quad * 8;
#pragma unroll
  for (int j = 0; j < 4; ++j)
    rb[j] = lB + (wc * 64 + j * 16 + mrow) * 64 + quad * 8;

  for (int k0 = 0; k0 < HID; k0 += 64) {
    __syncthreads();
#pragma unroll
    for (int i = 0; i < 4; ++i) {
      load16_lds(gA + (size_t)(i * 32) * HID, dA + i * 2048);
      load16_lds(gB + (size_t)(i * 32) * HID, dB + i * 2048);
    }
    gA += 64;
    gB += 64;
    __syncthreads();

#pragma unroll
    for (int kk = 0; kk < 2; ++kk) {
      bf16x8 af[4], bfr[4];
#pragma unroll
      for (int i = 0; i < 4; ++i)
        af[i] = *reinterpret_cast<const bf16x8*>(ra[i] + kk * 32);
#pragma unroll
      for (int j = 0; j < 4; ++j)
        bfr[j] = *reinterpret_cast<const bf16x8*>(rb[j] + kk * 32);
#pragma unroll
      for (int i = 0; i < 4; ++i)
#pragma unroll
        for (int j = 0; j < 4; ++j)
          acc[i][j] = __builtin_amdgcn_mfma_f32_16x16x32_bf16(af[i], bfr[j], acc[i][j], 0, 0, 0);
    }
  }

  // epilogue: verified C/D mapping: out row = quad*4 + r, out col = mrow.
  const int row_base = m0 + wr * 64 + quad * 4;
  const int col_base = n0 + wc * 64 + mrow;
#pragma unroll
  for (int i = 0; i < 4; ++i) {
#pragma unroll
    for (int j = 0; j < 4; ++j) {
#pragma unroll
      for (int r = 0; r < 4; ++r) {
        int row = row_base + i * 16 + r;
        Cb[(size_t)row * HID + col_base + j * 16] = f2bf(acc[i][j][r]);
      }
    }
  }
}

// ---- Kernel 3: RMS norm (proven; ~9 us, near its 7.6 us floor) ----
// out = C * 32 * rsqrt(sum C^2 + 400*eps*H) * norm_w   (/20 folded into scale)
__global__ __launch_bounds__(256) void rmsnorm_kernel(const unsigned short* __restrict__ Cb,
                                                      const float* __restrict__ nw,
                                                      float* __restrict__ out) {
  const int row = blockIdx.x * 4 + (threadIdx.x >> 6);
  const int lane = threadIdx.x & 63;
  const u16x8* src = reinterpret_cast<const u16x8*>(Cb) + (size_t)row * 128;
  f32x4 v[2][2];
  float ss = 0.f;
#pragma unroll
  for (int j = 0; j < 2; ++j) {
    u16x8 u = src[lane + j * 64];
#pragma unroll
    for (int h = 0; h < 2; ++h) {
#pragma unroll
      for (int e = 0; e < 4; ++e) {
        float f = bf2f(u[h * 4 + e]);
        v[j][h][e] = f;
        ss += f * f;
      }
    }
  }
#pragma unroll
  for (int off = 32; off > 0; off >>= 1) ss += __shfl_xor(ss, off, 64);
  const float scale = 32.0f * rsqrtf(ss + 0.4096f);  // 32=sqrt(H); 0.4096 = eps*H*400
  const f32x4* nwp = reinterpret_cast<const f32x4*>(nw);
  f32x4* dst = reinterpret_cast<f32x4*>(out) + (size_t)row * 256;
#pragma unroll
  for (int j = 0; j < 2; ++j) {
#pragma unroll
    for (int h = 0; h < 2; ++h) {
      const int fi = 2 * (lane + j * 64) + h;
      f32x4 wv = nwp[fi];
      f32x4 o = v[j][h] * scale * wv;
      __builtin_nontemporal_store(o, dst + fi);
    }
  }
}

extern "C" void kernel_launch(void* const* d_in, const int* in_sizes, int n_in,
                              void* d_out, int out_size, void* d_ws, size_t ws_size,
                              hipStream_t stream) {
  const float* x = (const float*)d_in[0];       // [2,4096,1024] fp32
  const float* conv_w = (const float*)d_in[1];  // [20,1024,1024] fp32
  const float* norm_w = (const float*)d_in[2];  // [1024] fp32
  float* out = (float*)d_out;                   // [2,4096,1024] fp32

  unsigned short* xb = (unsigned short*)d_ws;       // 16 MiB: A bf16
  unsigned short* wb = xb + (size_t)M_TOTAL * HID;  // +2 MiB: summed W bf16 [N][K]
  unsigned short* cb = wb + (size_t)HID * HID;      // +16 MiB: C bf16

  prep_kernel<<<512 + 2048, 256, 0, stream>>>(x, conv_w, xb, wb);
  gemm_kernel<<<(M_TOTAL / 128) * (HID / 128), 256, 0, stream>>>(xb, wb, cb);
  rmsnorm_kernel<<<M_TOTAL / 4, 256, 0, stream>>>(cb, norm_w, out);
}